// Round 15
// baseline (283.688 us; speedup 1.0000x reference)
//
#include <hip/hip_runtime.h>
#include <hip/hip_bf16.h>

// ---------- types ----------
typedef __bf16    bf16x8_t __attribute__((ext_vector_type(8)));
typedef __bf16    bf16x4_t __attribute__((ext_vector_type(4)));
typedef float     f32x4_t  __attribute__((ext_vector_type(4)));
typedef float     f32x16_t __attribute__((ext_vector_type(16)));
typedef _Float16  f16x8_t  __attribute__((ext_vector_type(8)));
typedef unsigned int u32x2_t __attribute__((ext_vector_type(2)));
typedef unsigned int u32x4_t __attribute__((ext_vector_type(4)));

static __device__ __forceinline__ f32x4_t mfma16(bf16x8_t a, bf16x8_t b, f32x4_t c) {
    return __builtin_amdgcn_mfma_f32_16x16x32_bf16(a, b, c, 0, 0, 0);
}
static __device__ __forceinline__ f32x16_t mfma32(bf16x8_t a, bf16x8_t b, f32x16_t c) {
    return __builtin_amdgcn_mfma_f32_32x32x16_bf16(a, b, c, 0, 0, 0);
}
static __device__ __forceinline__ f32x16_t zero16() {
    f32x16_t z;
#pragma unroll
    for (int j = 0; j < 16; j++) z[j] = 0.f;
    return z;
}

// async global->LDS 16B (m97 pattern); lds pointer must be wave-uniform
static __device__ __forceinline__ void async16(const __bf16* g, __bf16* l) {
    __builtin_amdgcn_global_load_lds(
        (const __attribute__((address_space(1))) unsigned int*)g,
        (__attribute__((address_space(3))) unsigned int*)l, 16, 0, 0);
}

// ---------- fused fp32 -> bf16 convert ----------
__global__ __launch_bounds__(256) void f2b_multi(const float* __restrict__ q,
                                                 const float* __restrict__ kv,
                                                 const float* __restrict__ wq,
                                                 const float* __restrict__ wk,
                                                 const float* __restrict__ wv,
                                                 const float* __restrict__ wo,
                                                 __bf16* __restrict__ qb,
                                                 __bf16* __restrict__ kvb,
                                                 __bf16* __restrict__ wqb,
                                                 __bf16* __restrict__ wkvb,
                                                 __bf16* __restrict__ wob,
                                                 float qscale) {
    int i = blockIdx.x * 256 + threadIdx.x;
    const float* src; __bf16* dst; int base; float scale = 1.0f;
    if (i < 1048576)      { src = q;  dst = qb;   base = 0; }
    else if (i < 3145728) { src = kv; dst = kvb;  base = 1048576; }
    else if (i < 3407872) { src = wq; dst = wqb;  base = 3145728; scale = qscale; }
    else if (i < 3670016) { src = wk; dst = wkvb; base = 3407872; }
    else if (i < 3932160) { src = wv; dst = wkvb + 1048576; base = 3670016; }
    else                  { src = wo; dst = wob;  base = 3932160; }
    int j = i - base;
    float4 v = reinterpret_cast<const float4*>(src)[j];
    bf16x4_t o;
    o[0] = (__bf16)(v.x * scale); o[1] = (__bf16)(v.y * scale);
    o[2] = (__bf16)(v.z * scale); o[3] = (__bf16)(v.w * scale);
    reinterpret_cast<bf16x4_t*>(dst)[j] = o;
}

// ---------- merged projection GEMM: Q + K + V in one launch ----------
// grid 1280: gid<256 -> Qp = qb*wqb^T (row-major out); else KV tiles.
// Khd/Vhd: per 64-s tile, 16B-CHUNK-COLUMN-MAJOR (see attn).
// K-loop: single-barrier 2-phase double-buffer.
__global__ __launch_bounds__(256) void proj_kernel(const __bf16* __restrict__ qb,
                                                   const __bf16* __restrict__ wqb,
                                                   const __bf16* __restrict__ kvb,
                                                   const __bf16* __restrict__ wkvb,
                                                   __bf16* __restrict__ Qp,
                                                   __bf16* __restrict__ Khd,
                                                   __bf16* __restrict__ Vhd,
                                                   const float* __restrict__ imp) {
    __shared__ __bf16 As[2][4096];
    __shared__ __bf16 Bs[2][4096];

    const int gid = blockIdx.x;
    const __bf16 *A, *B;
    long m0, n0;
    int mode;   // 0=Q, 1=K-part, 2=V-part
    if (gid < 256) {
        m0 = (long)(gid >> 3) * 128; n0 = (long)(gid & 7) * 128;
        A = qb; B = wqb; mode = 0;
    } else {
        int g2 = gid - 256;
        m0 = (long)(g2 >> 4) * 128; n0 = (long)(g2 & 15) * 128;
        A = kvb; B = wkvb; mode = (n0 < 1024) ? 1 : 2;
    }

    const int t    = threadIdx.x;
    const int w    = t >> 6;
    const int lane = t & 63;
    const int quad = lane >> 4;
    const int mn   = lane & 15;
    const int wm   = (w & 1) * 64;
    const int wn   = (w >> 1) * 64;

    const int  srow = t >> 2;
    const int  scol = (t & 3) * 8;
    const __bf16* gA = A + (m0 + srow) * 1024 + scol;
    const __bf16* gB = B + (n0 + srow) * 1024 + scol;

    f32x4_t acc[4][4];
#pragma unroll
    for (int i = 0; i < 4; i++)
#pragma unroll
        for (int j = 0; j < 4; j++) acc[i][j] = (f32x4_t){0.f, 0.f, 0.f, 0.f};

    // prologue: stage k0=0 into buf 0
    async16(gA,             &As[0][t * 8]);
    async16(gA + 64 * 1024, &As[0][2048 + t * 8]);
    async16(gB,             &Bs[0][t * 8]);
    async16(gB + 64 * 1024, &Bs[0][2048 + t * 8]);
    __syncthreads();

    for (int k0 = 0; k0 < 1024; k0 += 32) {
        const int cur = (k0 >> 5) & 1;
        // issue next k-step into buf^1 (last iter: re-stage in-range, dead buf)
        const int kn = (k0 + 32 < 1024) ? k0 + 32 : k0;
        async16(gA + kn,             &As[cur ^ 1][t * 8]);
        async16(gA + 64 * 1024 + kn, &As[cur ^ 1][2048 + t * 8]);
        async16(gB + kn,             &Bs[cur ^ 1][t * 8]);
        async16(gB + 64 * 1024 + kn, &Bs[cur ^ 1][2048 + t * 8]);

        bf16x8_t af[4], bf[4];
#pragma unroll
        for (int i = 0; i < 4; i++)
            af[i] = *(const bf16x8_t*)&As[cur][(wm + i * 16 + mn) * 32 + quad * 8];
#pragma unroll
        for (int j = 0; j < 4; j++)
            bf[j] = *(const bf16x8_t*)&Bs[cur][(wn + j * 16 + mn) * 32 + quad * 8];
#pragma unroll
        for (int i = 0; i < 4; i++)
#pragma unroll
            for (int j = 0; j < 4; j++) acc[i][j] = mfma16(af[i], bf[j], acc[i][j]);

        // single drain point: next buf staged + all waves done reading cur
        __syncthreads();
    }

    // epilogue staging: per-wave 64x64 region carved from the dbuf space
    __bf16* stg = (w < 2) ? &As[w][0] : &Bs[w - 2][0];
    // swizzled LDS addr: (row, col) -> row*64 + ((col>>3)^(row&7))*8 + (col&7)

    if (mode != 2) {
#pragma unroll
        for (int i = 0; i < 4; i++)
#pragma unroll
            for (int j = 0; j < 4; j++)
#pragma unroll
                for (int r = 0; r < 4; r++) {
                    int sl = i * 16 + quad * 4 + r;
                    int d  = j * 16 + mn;
                    stg[sl * 64 + (((d >> 3) ^ (sl & 7)) * 8) + (d & 7)] =
                        (__bf16)acc[i][j][r];
                }
    } else {
        // V: store V^T[d][s_local] (plain s), scaled by clamped imp.
        const int b_ = (int)((m0 + wm) >> 12);
        float scl[4];
#pragma unroll
        for (int r = 0; r < 4; r++)
            scl[r] = fmaxf(imp[b_ * 16 + quad * 4 + r], 1e-6f);
#pragma unroll
        for (int i = 0; i < 4; i++)
#pragma unroll
            for (int j = 0; j < 4; j++) {
                bf16x4_t pk;
#pragma unroll
                for (int r = 0; r < 4; r++) pk[r] = (__bf16)(acc[i][j][r] * scl[r]);
                int d  = j * 16 + mn;
                int s0 = i * 16 + quad * 4;
                *(bf16x4_t*)&stg[d * 64 + (((s0 >> 3) ^ (d & 7)) * 8) + (s0 & 7)] = pk;
            }
    }

    if (mode == 0) {
        __bf16* Cg = Qp + (m0 + wm) * 1024 + (n0 + wn);
#pragma unroll
        for (int it = 0; it < 8; it++) {
            int rowL = it * 8 + (lane >> 3);
            int cb   = lane & 7;
            bf16x8_t vv = *(const bf16x8_t*)&stg[rowL * 64 + ((cb ^ (rowL & 7)) * 8)];
            *(bf16x8_t*)&Cg[(long)rowL * 1024 + cb * 8] = vv;
        }
    } else {
        const int b_    = (int)((m0 + wm) >> 12);
        const int sbase = (int)((m0 + wm) & 4095);
        __bf16* dst;
        if (mode == 1) {
            int h_ = (int)((n0 + wn) >> 6);
            dst = Khd + (long)(b_ * 16 + h_) * 262144 + (long)sbase * 64;
        } else {
            int h_ = (int)((n0 + wn) >> 6) - 16;
            dst = Vhd + (long)(b_ * 16 + h_) * 262144 + (long)(sbase >> 6) * 4096;
        }
        // chunk-column-major store: chunk(row=lane, c=it) -> dst[it*512 + lane*8]
#pragma unroll
        for (int it = 0; it < 8; it++) {
            bf16x8_t vv = *(const bf16x8_t*)&stg[lane * 64 + ((it ^ (lane & 7)) * 8)];
            *(bf16x8_t*)&dst[it * 512 + lane * 8] = vv;
        }
    }
}

// ---------- flash attention: swapped-QK 32x32 MFMA, in-register P, ----------
// single-barrier 2-phase pipeline. 1D grid 1024, XCD-swizzled:
// gid = (bh&7) | qt<<3 | sp<<7 | (bh>>3)<<8.
// K and V both double-buffered in LDS (chunk-col-major, identity staging).
// LDS = 2*8K (Ks) + 2*8K (Vs) = 32 KB -> 4 blocks/CU. Best measured: ~82.5 us.
__global__ __launch_bounds__(256, 4) void attn_kernel(const __bf16* __restrict__ Qp,
                                                      const __bf16* __restrict__ Kh,
                                                      const __bf16* __restrict__ Vh,
                                                      const float* __restrict__ imp,
                                                      _Float16* __restrict__ Op,
                                                      float* __restrict__ Lp) {
    const int gid = blockIdx.x;
    const int qt  = (gid >> 3) & 15;
    const int sp  = (gid >> 7) & 1;
    const int bh  = ((gid >> 8) << 3) | (gid & 7);
    const int b   = bh >> 4;
    const int h   = bh & 15;
    const int t    = threadIdx.x;
    const int w    = t >> 6;
    const int lane = t & 63;
    const int hi   = lane >> 5;
    const int q32  = lane & 31;

    __shared__ __bf16 Ks[2][4096];   // double-buffered K tile (chunk-col-major)
    __shared__ __bf16 Vs[2][4096];   // double-buffered V^T tile (chunk-col-major)

    const long qrow0 = (long)b * 2048 + qt * 128 + w * 32;
    const __bf16* Kb = Kh + (long)bh * 262144;
    const __bf16* Vb = Vh + (long)bh * 262144;

    // identity staging offsets (per wave, per issue): src offset == LDS offset
    const int off0 = w * 512 + lane * 8;
    const int off1 = 2048 + w * 512 + lane * 8;

    // Q fragments (B-operand): lane col q=q32, k = ks*16 + hi*8 + e
    bf16x8_t aq[4];
#pragma unroll
    for (int ks = 0; ks < 4; ks++)
        aq[ks] = *(const bf16x8_t*)&Qp[(qrow0 + q32) * 1024 + h * 64 + ks * 16 + hi * 8];

    float lp[2][4];
#pragma unroll
    for (int j = 0; j < 2; j++)
#pragma unroll
        for (int r = 0; r < 4; r++) lp[j][r] = 0.f;
    f32x16_t o0 = zero16(), o1 = zero16();
    // persistent zero C-operand for the first QK mfma of each s-half
    const f32x16_t z16 = zero16();

    const int st0 = sp * 32;

    // prologue: stage K[st0] -> Ks[0], V[st0] -> Vs[0]; drained by barrier
    async16(Kb + (long)st0 * 4096 + off0, &Ks[0][off0]);
    async16(Kb + (long)st0 * 4096 + off1, &Ks[0][off1]);
    async16(Vb + (long)st0 * 4096 + off0, &Vs[0][off0]);
    async16(Vb + (long)st0 * 4096 + off1, &Vs[0][off1]);
    __syncthreads();

    // per-lane fragment base within a chunk-col-major tile:
    // elem(row, c) = c*512 + row*8; lane reads c = 2ks+hi, row = q32 (+32)
    const int lanebase = hi * 512 + q32 * 8;

    for (int it = 0; it < 32; ++it) {
        const int cur = it & 1;
        // clamped next tile (it==31 re-stages tile 31 into the dead buffer)
        const long stn = (long)(st0 + ((it < 31) ? it + 1 : it)) * 4096;

        // issue-next FIRST: K[it+1] + V[it+1] -> buf^1; deadline is the
        // end-of-iteration barrier -> full QK+softmax+PV latency cover
        async16(Kb + stn + off0, &Ks[cur ^ 1][off0]);
        async16(Kb + stn + off1, &Ks[cur ^ 1][off1]);
        async16(Vb + stn + off0, &Vs[cur ^ 1][off0]);
        async16(Vb + stn + off1, &Vs[cur ^ 1][off1]);

        const __bf16* Kc = &Ks[cur][lanebase];
        bf16x8_t pa[4];

        // per s-half of 32: swapped QK^T -> softmax -> in-register PA build
#pragma unroll
        for (int st2 = 0; st2 < 2; st2++) {
            __builtin_amdgcn_s_setprio(1);
            bf16x8_t kf0 = *(const bf16x8_t*)&Kc[0 * 1024 + st2 * 256];
            f32x16_t sc = mfma32(kf0, aq[0], z16);
#pragma unroll
            for (int ks = 1; ks < 4; ks++) {
                bf16x8_t kf = *(const bf16x8_t*)&Kc[ks * 1024 + st2 * 256];
                sc = mfma32(kf, aq[ks], sc);
            }
            __builtin_amdgcn_s_setprio(0);

            // lane holds p[s_loc][q32], s_loc = j + 8*g + 4*hi (reg = 4g+j)
            unsigned int wv[8];
#pragma unroll
            for (int g = 0; g < 4; g++) {
                float p0 = __builtin_amdgcn_exp2f(sc[4 * g + 0]);
                float p1 = __builtin_amdgcn_exp2f(sc[4 * g + 1]);
                float p2 = __builtin_amdgcn_exp2f(sc[4 * g + 2]);
                float p3 = __builtin_amdgcn_exp2f(sc[4 * g + 3]);
                lp[g & 1][0] += p0; lp[g & 1][1] += p1;
                lp[g & 1][2] += p2; lp[g & 1][3] += p3;
                bf16x4_t pk;
                pk[0] = (__bf16)p0; pk[1] = (__bf16)p1;
                pk[2] = (__bf16)p2; pk[3] = (__bf16)p3;
                u32x2_t uu = __builtin_bit_cast(u32x2_t, pk);
                wv[2 * g]     = uu[0];
                wv[2 * g + 1] = uu[1];
            }
            // half-exchange: swap lanes>=32 of first arg with lanes<32 of second.
            u32x2_t s02 = __builtin_amdgcn_permlane32_swap(wv[0], wv[2], false, false);
            u32x2_t s13 = __builtin_amdgcn_permlane32_swap(wv[1], wv[3], false, false);
            u32x2_t s46 = __builtin_amdgcn_permlane32_swap(wv[4], wv[6], false, false);
            u32x2_t s57 = __builtin_amdgcn_permlane32_swap(wv[5], wv[7], false, false);
            u32x4_t pu0 = {s02[0], s13[0], s02[1], s13[1]};
            u32x4_t pu1 = {s46[0], s57[0], s46[1], s57[1]};
            pa[st2 * 2 + 0] = __builtin_bit_cast(bf16x8_t, pu0);
            pa[st2 * 2 + 1] = __builtin_bit_cast(bf16x8_t, pu1);
        }

        // PV: o[q][d] += sum_s PA[q][s] * V[s][d]; Vs rows = d, chunks = s/8.
        const __bf16* Vc = &Vs[cur][lanebase];
        __builtin_amdgcn_s_setprio(1);
#pragma unroll
        for (int ks = 0; ks < 4; ks++) {
            bf16x8_t v0 = *(const bf16x8_t*)&Vc[ks * 1024];
            bf16x8_t v1 = *(const bf16x8_t*)&Vc[ks * 1024 + 256];
            o0 = mfma32(pa[ks], v0, o0);
            o1 = mfma32(pa[ks], v1, o1);
        }
        __builtin_amdgcn_s_setprio(0);

        // single drain point: next K/V staged (covered by whole iteration),
        // and all waves done reading buf[cur] before it is overwritten.
        __syncthreads();
    }

    // epilogue: l[q] = sum exp * imp[sensor], sensor = 4*hi + 8*j + r
    float lsum = 0.f;
#pragma unroll
    for (int j = 0; j < 2; j++)
#pragma unroll
        for (int r = 0; r < 4; r++)
            lsum += lp[j][r] * fmaxf(imp[b * 16 + 4 * hi + 8 * j + r], 1e-6f);
    lsum += __shfl_xor(lsum, 32);
    if (lane < 32)
        Lp[((long)sp * 4096 + qrow0 + q32) * 16 + h] = lsum;

#pragma unroll
    for (int j = 0; j < 16; j++) {
        int q_loc = (j & 3) + 8 * (j >> 2) + 4 * hi;
        long row  = (long)sp * 4096 + qrow0 + q_loc;
        Op[row * 1024 + h * 64 + 0 * 32 + q32] = (_Float16)o0[j];
        Op[row * 1024 + h * 64 + 1 * 32 + q32] = (_Float16)o1[j];
    }
}

// ---------- combine: Y = (o0+o1)/(l0+l1) ----------
__global__ __launch_bounds__(256) void combine_kernel(const _Float16* __restrict__ Op,
                                                      const float* __restrict__ Lp,
                                                      __bf16* __restrict__ Y) {
    int tid = blockIdx.x * 256 + threadIdx.x;
    int row = tid >> 7;
    int cg  = tid & 127;
    int h   = cg >> 3;
    f16x8_t o0 = *(const f16x8_t*)&Op[(long)row * 1024 + cg * 8];
    f16x8_t o1 = *(const f16x8_t*)&Op[(long)(4096 + row) * 1024 + cg * 8];
    float inv = 1.0f / (Lp[row * 16 + h] + Lp[(4096 + row) * 16 + h]);
    bf16x8_t y;
#pragma unroll
    for (int j = 0; j < 8; j++) y[j] = (__bf16)(((float)o0[j] + (float)o1[j]) * inv);
    *(bf16x8_t*)&Y[(long)row * 1024 + cg * 8] = y;
}

// ---------- output GEMM, split-K x2: P[kh] = A[M, kh-half] * B[N, kh-half]^T ----------
// grid dim3(16, 32): kh = blockIdx.x>>3, n-tile = blockIdx.x&7, m-tile = blockIdx.y.
// Single-barrier 2-phase double-buffer K-loop.
__global__ __launch_bounds__(256) void gemm_out_kernel(const __bf16* __restrict__ A,
                                                       const __bf16* __restrict__ B,
                                                       float* __restrict__ P) {
    __shared__ __bf16 As[2][4096];
    __shared__ __bf16 Bs[2][4096];

    const int  kh = blockIdx.x >> 3;
    const long n0 = (long)(blockIdx.x & 7) * 128;
    const long m0 = (long)blockIdx.y * 128;
    const int  kb = kh * 512;
    float* C = P + (long)kh * 4194304;

    const int t    = threadIdx.x;
    const int w    = t >> 6;
    const int lane = t & 63;
    const int quad = lane >> 4;
    const int mn   = lane & 15;
    const int wm   = (w & 1) * 64;
    const int wn   = (w >> 1) * 64;

    const int  srow = t >> 2;
    const int  scol = (t & 3) * 8;
    const __bf16* gA = A + (m0 + srow) * 1024 + kb + scol;
    const __bf16* gB = B + (n0 + srow) * 1024 + kb + scol;

    f32x4_t acc[4][4];
#pragma unroll
    for (int i = 0; i < 4; i++)
#pragma unroll
        for (int j = 0; j < 4; j++) acc[i][j] = (f32x4_t){0.f, 0.f, 0.f, 0.f};

    // prologue: stage k0=0 into buf 0
    async16(gA,             &As[0][t * 8]);
    async16(gA + 64 * 1024, &As[0][2048 + t * 8]);
    async16(gB,             &Bs[0][t * 8]);
    async16(gB + 64 * 1024, &Bs[0][2048 + t * 8]);
    __syncthreads();

    for (int k0 = 0; k0 < 512; k0 += 32) {
        const int cur = (k0 >> 5) & 1;
        const int kn = (k0 + 32 < 512) ? k0 + 32 : k0;
        async16(gA + kn,             &As[cur ^ 1][t * 8]);
        async16(gA + 64 * 1024 + kn, &As[cur ^ 1][2048 + t * 8]);
        async16(gB + kn,             &Bs[cur ^ 1][t * 8]);
        async16(gB + 64 * 1024 + kn, &Bs[cur ^ 1][2048 + t * 8]);

        bf16x8_t af[4], bf[4];
#pragma unroll
        for (int i = 0; i < 4; i++)
            af[i] = *(const bf16x8_t*)&As[cur][(wm + i * 16 + mn) * 32 + quad * 8];
#pragma unroll
        for (int j = 0; j < 4; j++)
            bf[j] = *(const bf16x8_t*)&Bs[cur][(wn + j * 16 + mn) * 32 + quad * 8];
#pragma unroll
        for (int i = 0; i < 4; i++)
#pragma unroll
            for (int j = 0; j < 4; j++) acc[i][j] = mfma16(af[i], bf[j], acc[i][j]);

        __syncthreads();
    }

#pragma unroll
    for (int i = 0; i < 4; i++)
#pragma unroll
        for (int j = 0; j < 4; j++)
#pragma unroll
            for (int r = 0; r < 4; r++) {
                long row = m0 + wm + i * 16 + quad * 4 + r;
                long col = n0 + wn + j * 16 + mn;
                C[row * 1024 + col] = acc[i][j][r];
            }
}

// ---------- combine2: out = P0 + P1 (fp32 float4) ----------
__global__ __launch_bounds__(256) void combine2_kernel(const float* __restrict__ P0,
                                                       const float* __restrict__ P1,
                                                       float* __restrict__ out) {
    int i = blockIdx.x * 256 + threadIdx.x;   // float4 index, 0..1048575
    float4 a = reinterpret_cast<const float4*>(P0)[i];
    float4 b = reinterpret_cast<const float4*>(P1)[i];
    float4 c; c.x = a.x + b.x; c.y = a.y + b.y; c.z = a.z + b.z; c.w = a.w + b.w;
    reinterpret_cast<float4*>(out)[i] = c;
}

// ---------- launch ----------
extern "C" void kernel_launch(void* const* d_in, const int* in_sizes, int n_in,
                              void* d_out, int out_size, void* d_ws, size_t ws_size,
                              hipStream_t stream) {
    const float* q_f  = (const float*)d_in[0];
    const float* kv_f = (const float*)d_in[1];
    const float* imp  = (const float*)d_in[2];
    const float* wq_f = (const float*)d_in[3];
    const float* wk_f = (const float*)d_in[4];
    const float* wv_f = (const float*)d_in[5];
    const float* wo_f = (const float*)d_in[6];

    char* ws = (char*)d_ws;
    const size_t MB = 1ull << 20;
    __bf16*   qb    = (__bf16*)(ws + 0);            // 8 MB   (stage A)
    __bf16*   kvb   = (__bf16*)(ws + 8 * MB);       // 16 MB  (stage A)
    __bf16*   wqb   = (__bf16*)(ws + 24 * MB);      // 2 MB   (stage A)
    __bf16*   wkvb  = (__bf16*)(ws + 26 * MB);      // 4 MB   (stage A)
    _Float16* Opart = (_Float16*)(ws + 0);          // 16 MB  (stage B)
    float*    Lpart = (float*)(ws + 16 * MB);       // 0.5 MB (stage B)
    __bf16*   Yb    = (__bf16*)(ws + 17 * MB);      // 8 MB   (stage B)
    __bf16*   wob   = (__bf16*)(ws + 30 * MB);      // 2 MB
    __bf16*   Qp    = (__bf16*)(ws + 32 * MB);      // 8 MB
    __bf16*   Khd   = (__bf16*)(ws + 40 * MB);      // 16 MB  (stage C: gemm partials)
    __bf16*   Vhd   = (__bf16*)(ws + 56 * MB);      // 16 MB  (stage C: gemm partials)
    float*    Gp    = (float*)(ws + 40 * MB);       // 32 MB  (after attn: P0|P1)

    const float QSCALE = 0.125f * 1.4426950408889634f;

    f2b_multi<<<16384, 256, 0, stream>>>(q_f, kv_f, wq_f, wk_f, wv_f, wo_f,
                                         qb, kvb, wqb, wkvb, wob, QSCALE);

    proj_kernel<<<1280, 256, 0, stream>>>(qb, wqb, kvb, wkvb, Qp, Khd, Vhd, imp);

    attn_kernel<<<1024, 256, 0, stream>>>(Qp, Khd, Vhd, imp, Opart, Lpart);
    combine_kernel<<<2048, 256, 0, stream>>>(Opart, Lpart, Yb);

    gemm_out_kernel<<<dim3(16, 32), 256, 0, stream>>>(Yb, wob, Gp);
    combine2_kernel<<<4096, 256, 0, stream>>>(Gp, Gp + 4194304, (float*)d_out);
}

// Round 16
// 282.864 us; speedup vs baseline: 1.0029x; 1.0029x over previous
//
#include <hip/hip_runtime.h>
#include <hip/hip_bf16.h>

// ---------- types ----------
typedef __bf16    bf16x8_t __attribute__((ext_vector_type(8)));
typedef __bf16    bf16x4_t __attribute__((ext_vector_type(4)));
typedef float     f32x4_t  __attribute__((ext_vector_type(4)));
typedef float     f32x16_t __attribute__((ext_vector_type(16)));
typedef _Float16  f16x8_t  __attribute__((ext_vector_type(8)));
typedef unsigned int u32x2_t __attribute__((ext_vector_type(2)));
typedef unsigned int u32x4_t __attribute__((ext_vector_type(4)));

static __device__ __forceinline__ f32x4_t mfma16(bf16x8_t a, bf16x8_t b, f32x4_t c) {
    return __builtin_amdgcn_mfma_f32_16x16x32_bf16(a, b, c, 0, 0, 0);
}
static __device__ __forceinline__ f32x16_t mfma32(bf16x8_t a, bf16x8_t b, f32x16_t c) {
    return __builtin_amdgcn_mfma_f32_32x32x16_bf16(a, b, c, 0, 0, 0);
}
static __device__ __forceinline__ f32x16_t zero16() {
    f32x16_t z;
#pragma unroll
    for (int j = 0; j < 16; j++) z[j] = 0.f;
    return z;
}

// async global->LDS 16B (m97 pattern); lds pointer must be wave-uniform
static __device__ __forceinline__ void async16(const __bf16* g, __bf16* l) {
    __builtin_amdgcn_global_load_lds(
        (const __attribute__((address_space(1))) unsigned int*)g,
        (__attribute__((address_space(3))) unsigned int*)l, 16, 0, 0);
}

// ---------- fused fp32 -> bf16 convert ----------
__global__ __launch_bounds__(256) void f2b_multi(const float* __restrict__ q,
                                                 const float* __restrict__ kv,
                                                 const float* __restrict__ wq,
                                                 const float* __restrict__ wk,
                                                 const float* __restrict__ wv,
                                                 const float* __restrict__ wo,
                                                 __bf16* __restrict__ qb,
                                                 __bf16* __restrict__ kvb,
                                                 __bf16* __restrict__ wqb,
                                                 __bf16* __restrict__ wkvb,
                                                 __bf16* __restrict__ wob,
                                                 float qscale) {
    int i = blockIdx.x * 256 + threadIdx.x;
    const float* src; __bf16* dst; int base; float scale = 1.0f;
    if (i < 1048576)      { src = q;  dst = qb;   base = 0; }
    else if (i < 3145728) { src = kv; dst = kvb;  base = 1048576; }
    else if (i < 3407872) { src = wq; dst = wqb;  base = 3145728; scale = qscale; }
    else if (i < 3670016) { src = wk; dst = wkvb; base = 3407872; }
    else if (i < 3932160) { src = wv; dst = wkvb + 1048576; base = 3670016; }
    else                  { src = wo; dst = wob;  base = 3932160; }
    int j = i - base;
    float4 v = reinterpret_cast<const float4*>(src)[j];
    bf16x4_t o;
    o[0] = (__bf16)(v.x * scale); o[1] = (__bf16)(v.y * scale);
    o[2] = (__bf16)(v.z * scale); o[3] = (__bf16)(v.w * scale);
    reinterpret_cast<bf16x4_t*>(dst)[j] = o;
}

// ---------- merged projection GEMM: Q + K + V in one launch ----------
// grid 1280: gid<256 -> Qp = qb*wqb^T (row-major out); else KV tiles.
// Khd/Vhd: per 64-s tile, 16B-CHUNK-COLUMN-MAJOR (see attn).
// K-loop: single-barrier 2-phase double-buffer.
__global__ __launch_bounds__(256) void proj_kernel(const __bf16* __restrict__ qb,
                                                   const __bf16* __restrict__ wqb,
                                                   const __bf16* __restrict__ kvb,
                                                   const __bf16* __restrict__ wkvb,
                                                   __bf16* __restrict__ Qp,
                                                   __bf16* __restrict__ Khd,
                                                   __bf16* __restrict__ Vhd,
                                                   const float* __restrict__ imp) {
    __shared__ __bf16 As[2][4096];
    __shared__ __bf16 Bs[2][4096];

    const int gid = blockIdx.x;
    const __bf16 *A, *B;
    long m0, n0;
    int mode;   // 0=Q, 1=K-part, 2=V-part
    if (gid < 256) {
        m0 = (long)(gid >> 3) * 128; n0 = (long)(gid & 7) * 128;
        A = qb; B = wqb; mode = 0;
    } else {
        int g2 = gid - 256;
        m0 = (long)(g2 >> 4) * 128; n0 = (long)(g2 & 15) * 128;
        A = kvb; B = wkvb; mode = (n0 < 1024) ? 1 : 2;
    }

    const int t    = threadIdx.x;
    const int w    = t >> 6;
    const int lane = t & 63;
    const int quad = lane >> 4;
    const int mn   = lane & 15;
    const int wm   = (w & 1) * 64;
    const int wn   = (w >> 1) * 64;

    const int  srow = t >> 2;
    const int  scol = (t & 3) * 8;
    const __bf16* gA = A + (m0 + srow) * 1024 + scol;
    const __bf16* gB = B + (n0 + srow) * 1024 + scol;

    f32x4_t acc[4][4];
#pragma unroll
    for (int i = 0; i < 4; i++)
#pragma unroll
        for (int j = 0; j < 4; j++) acc[i][j] = (f32x4_t){0.f, 0.f, 0.f, 0.f};

    // prologue: stage k0=0 into buf 0
    async16(gA,             &As[0][t * 8]);
    async16(gA + 64 * 1024, &As[0][2048 + t * 8]);
    async16(gB,             &Bs[0][t * 8]);
    async16(gB + 64 * 1024, &Bs[0][2048 + t * 8]);
    __syncthreads();

    for (int k0 = 0; k0 < 1024; k0 += 32) {
        const int cur = (k0 >> 5) & 1;
        // issue next k-step into buf^1 (last iter: re-stage in-range, dead buf)
        const int kn = (k0 + 32 < 1024) ? k0 + 32 : k0;
        async16(gA + kn,             &As[cur ^ 1][t * 8]);
        async16(gA + 64 * 1024 + kn, &As[cur ^ 1][2048 + t * 8]);
        async16(gB + kn,             &Bs[cur ^ 1][t * 8]);
        async16(gB + 64 * 1024 + kn, &Bs[cur ^ 1][2048 + t * 8]);

        bf16x8_t af[4], bf[4];
#pragma unroll
        for (int i = 0; i < 4; i++)
            af[i] = *(const bf16x8_t*)&As[cur][(wm + i * 16 + mn) * 32 + quad * 8];
#pragma unroll
        for (int j = 0; j < 4; j++)
            bf[j] = *(const bf16x8_t*)&Bs[cur][(wn + j * 16 + mn) * 32 + quad * 8];
#pragma unroll
        for (int i = 0; i < 4; i++)
#pragma unroll
            for (int j = 0; j < 4; j++) acc[i][j] = mfma16(af[i], bf[j], acc[i][j]);

        // single drain point: next buf staged + all waves done reading cur
        __syncthreads();
    }

    // epilogue staging: per-wave 64x64 region carved from the dbuf space
    __bf16* stg = (w < 2) ? &As[w][0] : &Bs[w - 2][0];
    // swizzled LDS addr: (row, col) -> row*64 + ((col>>3)^(row&7))*8 + (col&7)

    if (mode != 2) {
#pragma unroll
        for (int i = 0; i < 4; i++)
#pragma unroll
            for (int j = 0; j < 4; j++)
#pragma unroll
                for (int r = 0; r < 4; r++) {
                    int sl = i * 16 + quad * 4 + r;
                    int d  = j * 16 + mn;
                    stg[sl * 64 + (((d >> 3) ^ (sl & 7)) * 8) + (d & 7)] =
                        (__bf16)acc[i][j][r];
                }
    } else {
        // V: store V^T[d][s_local] (plain s), scaled by clamped imp.
        const int b_ = (int)((m0 + wm) >> 12);
        float scl[4];
#pragma unroll
        for (int r = 0; r < 4; r++)
            scl[r] = fmaxf(imp[b_ * 16 + quad * 4 + r], 1e-6f);
#pragma unroll
        for (int i = 0; i < 4; i++)
#pragma unroll
            for (int j = 0; j < 4; j++) {
                bf16x4_t pk;
#pragma unroll
                for (int r = 0; r < 4; r++) pk[r] = (__bf16)(acc[i][j][r] * scl[r]);
                int d  = j * 16 + mn;
                int s0 = i * 16 + quad * 4;
                *(bf16x4_t*)&stg[d * 64 + (((s0 >> 3) ^ (d & 7)) * 8) + (s0 & 7)] = pk;
            }
    }

    if (mode == 0) {
        __bf16* Cg = Qp + (m0 + wm) * 1024 + (n0 + wn);
#pragma unroll
        for (int it = 0; it < 8; it++) {
            int rowL = it * 8 + (lane >> 3);
            int cb   = lane & 7;
            bf16x8_t vv = *(const bf16x8_t*)&stg[rowL * 64 + ((cb ^ (rowL & 7)) * 8)];
            *(bf16x8_t*)&Cg[(long)rowL * 1024 + cb * 8] = vv;
        }
    } else {
        const int b_    = (int)((m0 + wm) >> 12);
        const int sbase = (int)((m0 + wm) & 4095);
        __bf16* dst;
        if (mode == 1) {
            int h_ = (int)((n0 + wn) >> 6);
            dst = Khd + (long)(b_ * 16 + h_) * 262144 + (long)sbase * 64;
        } else {
            int h_ = (int)((n0 + wn) >> 6) - 16;
            dst = Vhd + (long)(b_ * 16 + h_) * 262144 + (long)(sbase >> 6) * 4096;
        }
        // chunk-column-major store: chunk(row=lane, c=it) -> dst[it*512 + lane*8]
#pragma unroll
        for (int it = 0; it < 8; it++) {
            bf16x8_t vv = *(const bf16x8_t*)&stg[lane * 64 + ((it ^ (lane & 7)) * 8)];
            *(bf16x8_t*)&dst[it * 512 + lane * 8] = vv;
        }
    }
}

// ---------- flash attention: swapped-QK 32x32 MFMA, in-register P, ----------
// single-barrier 2-phase pipeline. 1D grid 1024, XCD-swizzled:
// gid = (bh&7) | qt<<3 | sp<<7 | (bh>>3)<<8.
// K and V both double-buffered in LDS (chunk-col-major, identity staging).
// LDS = 2*8K (Ks) + 2*8K (Vs) = 32 KB -> 4 blocks/CU. Best measured: ~82.5 us.
__global__ __launch_bounds__(256, 4) void attn_kernel(const __bf16* __restrict__ Qp,
                                                      const __bf16* __restrict__ Kh,
                                                      const __bf16* __restrict__ Vh,
                                                      const float* __restrict__ imp,
                                                      _Float16* __restrict__ Op,
                                                      float* __restrict__ Lp) {
    const int gid = blockIdx.x;
    const int qt  = (gid >> 3) & 15;
    const int sp  = (gid >> 7) & 1;
    const int bh  = ((gid >> 8) << 3) | (gid & 7);
    const int b   = bh >> 4;
    const int h   = bh & 15;
    const int t    = threadIdx.x;
    const int w    = t >> 6;
    const int lane = t & 63;
    const int hi   = lane >> 5;
    const int q32  = lane & 31;

    __shared__ __bf16 Ks[2][4096];   // double-buffered K tile (chunk-col-major)
    __shared__ __bf16 Vs[2][4096];   // double-buffered V^T tile (chunk-col-major)

    const long qrow0 = (long)b * 2048 + qt * 128 + w * 32;
    const __bf16* Kb = Kh + (long)bh * 262144;
    const __bf16* Vb = Vh + (long)bh * 262144;

    // identity staging offsets (per wave, per issue): src offset == LDS offset
    const int off0 = w * 512 + lane * 8;
    const int off1 = 2048 + w * 512 + lane * 8;

    // Q fragments (B-operand): lane col q=q32, k = ks*16 + hi*8 + e
    bf16x8_t aq[4];
#pragma unroll
    for (int ks = 0; ks < 4; ks++)
        aq[ks] = *(const bf16x8_t*)&Qp[(qrow0 + q32) * 1024 + h * 64 + ks * 16 + hi * 8];

    float lp[2][4];
#pragma unroll
    for (int j = 0; j < 2; j++)
#pragma unroll
        for (int r = 0; r < 4; r++) lp[j][r] = 0.f;
    f32x16_t o0 = zero16(), o1 = zero16();
    // persistent zero C-operand for the first QK mfma of each s-half
    const f32x16_t z16 = zero16();

    const int st0 = sp * 32;

    // prologue: stage K[st0] -> Ks[0], V[st0] -> Vs[0]; drained by barrier
    async16(Kb + (long)st0 * 4096 + off0, &Ks[0][off0]);
    async16(Kb + (long)st0 * 4096 + off1, &Ks[0][off1]);
    async16(Vb + (long)st0 * 4096 + off0, &Vs[0][off0]);
    async16(Vb + (long)st0 * 4096 + off1, &Vs[0][off1]);
    __syncthreads();

    // per-lane fragment base within a chunk-col-major tile:
    // elem(row, c) = c*512 + row*8; lane reads c = 2ks+hi, row = q32 (+32)
    const int lanebase = hi * 512 + q32 * 8;

    for (int it = 0; it < 32; ++it) {
        const int cur = it & 1;
        // clamped next tile (it==31 re-stages tile 31 into the dead buffer)
        const long stn = (long)(st0 + ((it < 31) ? it + 1 : it)) * 4096;

        // issue-next FIRST: K[it+1] + V[it+1] -> buf^1; deadline is the
        // end-of-iteration barrier -> full QK+softmax+PV latency cover
        async16(Kb + stn + off0, &Ks[cur ^ 1][off0]);
        async16(Kb + stn + off1, &Ks[cur ^ 1][off1]);
        async16(Vb + stn + off0, &Vs[cur ^ 1][off0]);
        async16(Vb + stn + off1, &Vs[cur ^ 1][off1]);

        const __bf16* Kc = &Ks[cur][lanebase];
        bf16x8_t pa[4];

        // per s-half of 32: swapped QK^T -> softmax -> in-register PA build
#pragma unroll
        for (int st2 = 0; st2 < 2; st2++) {
            __builtin_amdgcn_s_setprio(1);
            bf16x8_t kf0 = *(const bf16x8_t*)&Kc[0 * 1024 + st2 * 256];
            f32x16_t sc = mfma32(kf0, aq[0], z16);
#pragma unroll
            for (int ks = 1; ks < 4; ks++) {
                bf16x8_t kf = *(const bf16x8_t*)&Kc[ks * 1024 + st2 * 256];
                sc = mfma32(kf, aq[ks], sc);
            }
            __builtin_amdgcn_s_setprio(0);

            // lane holds p[s_loc][q32], s_loc = j + 8*g + 4*hi (reg = 4g+j)
            unsigned int wv[8];
#pragma unroll
            for (int g = 0; g < 4; g++) {
                float p0 = __builtin_amdgcn_exp2f(sc[4 * g + 0]);
                float p1 = __builtin_amdgcn_exp2f(sc[4 * g + 1]);
                float p2 = __builtin_amdgcn_exp2f(sc[4 * g + 2]);
                float p3 = __builtin_amdgcn_exp2f(sc[4 * g + 3]);
                lp[g & 1][0] += p0; lp[g & 1][1] += p1;
                lp[g & 1][2] += p2; lp[g & 1][3] += p3;
                bf16x4_t pk;
                pk[0] = (__bf16)p0; pk[1] = (__bf16)p1;
                pk[2] = (__bf16)p2; pk[3] = (__bf16)p3;
                u32x2_t uu = __builtin_bit_cast(u32x2_t, pk);
                wv[2 * g]     = uu[0];
                wv[2 * g + 1] = uu[1];
            }
            // half-exchange: swap lanes>=32 of first arg with lanes<32 of second.
            u32x2_t s02 = __builtin_amdgcn_permlane32_swap(wv[0], wv[2], false, false);
            u32x2_t s13 = __builtin_amdgcn_permlane32_swap(wv[1], wv[3], false, false);
            u32x2_t s46 = __builtin_amdgcn_permlane32_swap(wv[4], wv[6], false, false);
            u32x2_t s57 = __builtin_amdgcn_permlane32_swap(wv[5], wv[7], false, false);
            u32x4_t pu0 = {s02[0], s13[0], s02[1], s13[1]};
            u32x4_t pu1 = {s46[0], s57[0], s46[1], s57[1]};
            pa[st2 * 2 + 0] = __builtin_bit_cast(bf16x8_t, pu0);
            pa[st2 * 2 + 1] = __builtin_bit_cast(bf16x8_t, pu1);
        }

        // PV: o[q][d] += sum_s PA[q][s] * V[s][d]; Vs rows = d, chunks = s/8.
        const __bf16* Vc = &Vs[cur][lanebase];
        __builtin_amdgcn_s_setprio(1);
#pragma unroll
        for (int ks = 0; ks < 4; ks++) {
            bf16x8_t v0 = *(const bf16x8_t*)&Vc[ks * 1024];
            bf16x8_t v1 = *(const bf16x8_t*)&Vc[ks * 1024 + 256];
            o0 = mfma32(pa[ks], v0, o0);
            o1 = mfma32(pa[ks], v1, o1);
        }
        __builtin_amdgcn_s_setprio(0);

        // single drain point: next K/V staged (covered by whole iteration),
        // and all waves done reading buf[cur] before it is overwritten.
        __syncthreads();
    }

    // epilogue: l[q] = sum exp * imp[sensor], sensor = 4*hi + 8*j + r
    float lsum = 0.f;
#pragma unroll
    for (int j = 0; j < 2; j++)
#pragma unroll
        for (int r = 0; r < 4; r++)
            lsum += lp[j][r] * fmaxf(imp[b * 16 + 4 * hi + 8 * j + r], 1e-6f);
    lsum += __shfl_xor(lsum, 32);
    if (lane < 32)
        Lp[((long)sp * 4096 + qrow0 + q32) * 16 + h] = lsum;

#pragma unroll
    for (int j = 0; j < 16; j++) {
        int q_loc = (j & 3) + 8 * (j >> 2) + 4 * hi;
        long row  = (long)sp * 4096 + qrow0 + q_loc;
        Op[row * 1024 + h * 64 + 0 * 32 + q32] = (_Float16)o0[j];
        Op[row * 1024 + h * 64 + 1 * 32 + q32] = (_Float16)o1[j];
    }
}

// ---------- combine: Y = (o0+o1)/(l0+l1) ----------
__global__ __launch_bounds__(256) void combine_kernel(const _Float16* __restrict__ Op,
                                                      const float* __restrict__ Lp,
                                                      __bf16* __restrict__ Y) {
    int tid = blockIdx.x * 256 + threadIdx.x;
    int row = tid >> 7;
    int cg  = tid & 127;
    int h   = cg >> 3;
    f16x8_t o0 = *(const f16x8_t*)&Op[(long)row * 1024 + cg * 8];
    f16x8_t o1 = *(const f16x8_t*)&Op[(long)(4096 + row) * 1024 + cg * 8];
    float inv = 1.0f / (Lp[row * 16 + h] + Lp[(4096 + row) * 16 + h]);
    bf16x8_t y;
#pragma unroll
    for (int j = 0; j < 8; j++) y[j] = (__bf16)(((float)o0[j] + (float)o1[j]) * inv);
    *(bf16x8_t*)&Y[(long)row * 1024 + cg * 8] = y;
}

// ---------- output GEMM, full-K: out = Yb * wob^T, fp32 stored DIRECTLY ----------
// grid dim3(8, 32): n-tile = blockIdx.x, m-tile = blockIdx.y (256 blocks,
// 1/CU). K=1024 in one block (32 2-phase iterations) -> no split-K partials,
// no combine2 kernel, no 32MB Gp round-trip (-80 MB HBM, -1 launch).
__global__ __launch_bounds__(256) void gemm_out_kernel(const __bf16* __restrict__ A,
                                                       const __bf16* __restrict__ B,
                                                       float* __restrict__ C) {
    __shared__ __bf16 As[2][4096];
    __shared__ __bf16 Bs[2][4096];

    const long n0 = (long)blockIdx.x * 128;
    const long m0 = (long)blockIdx.y * 128;

    const int t    = threadIdx.x;
    const int w    = t >> 6;
    const int lane = t & 63;
    const int quad = lane >> 4;
    const int mn   = lane & 15;
    const int wm   = (w & 1) * 64;
    const int wn   = (w >> 1) * 64;

    const int  srow = t >> 2;
    const int  scol = (t & 3) * 8;
    const __bf16* gA = A + (m0 + srow) * 1024 + scol;
    const __bf16* gB = B + (n0 + srow) * 1024 + scol;

    f32x4_t acc[4][4];
#pragma unroll
    for (int i = 0; i < 4; i++)
#pragma unroll
        for (int j = 0; j < 4; j++) acc[i][j] = (f32x4_t){0.f, 0.f, 0.f, 0.f};

    // prologue: stage k0=0 into buf 0
    async16(gA,             &As[0][t * 8]);
    async16(gA + 64 * 1024, &As[0][2048 + t * 8]);
    async16(gB,             &Bs[0][t * 8]);
    async16(gB + 64 * 1024, &Bs[0][2048 + t * 8]);
    __syncthreads();

    for (int k0 = 0; k0 < 1024; k0 += 32) {
        const int cur = (k0 >> 5) & 1;
        const int kn = (k0 + 32 < 1024) ? k0 + 32 : k0;
        async16(gA + kn,             &As[cur ^ 1][t * 8]);
        async16(gA + 64 * 1024 + kn, &As[cur ^ 1][2048 + t * 8]);
        async16(gB + kn,             &Bs[cur ^ 1][t * 8]);
        async16(gB + 64 * 1024 + kn, &Bs[cur ^ 1][2048 + t * 8]);

        bf16x8_t af[4], bf[4];
#pragma unroll
        for (int i = 0; i < 4; i++)
            af[i] = *(const bf16x8_t*)&As[cur][(wm + i * 16 + mn) * 32 + quad * 8];
#pragma unroll
        for (int j = 0; j < 4; j++)
            bf[j] = *(const bf16x8_t*)&Bs[cur][(wn + j * 16 + mn) * 32 + quad * 8];
#pragma unroll
        for (int i = 0; i < 4; i++)
#pragma unroll
            for (int j = 0; j < 4; j++) acc[i][j] = mfma16(af[i], bf[j], acc[i][j]);

        __syncthreads();
    }

#pragma unroll
    for (int i = 0; i < 4; i++)
#pragma unroll
        for (int j = 0; j < 4; j++)
#pragma unroll
            for (int r = 0; r < 4; r++) {
                long row = m0 + wm + i * 16 + quad * 4 + r;
                long col = n0 + wn + j * 16 + mn;
                C[row * 1024 + col] = acc[i][j][r];
            }
}

// ---------- launch ----------
extern "C" void kernel_launch(void* const* d_in, const int* in_sizes, int n_in,
                              void* d_out, int out_size, void* d_ws, size_t ws_size,
                              hipStream_t stream) {
    const float* q_f  = (const float*)d_in[0];
    const float* kv_f = (const float*)d_in[1];
    const float* imp  = (const float*)d_in[2];
    const float* wq_f = (const float*)d_in[3];
    const float* wk_f = (const float*)d_in[4];
    const float* wv_f = (const float*)d_in[5];
    const float* wo_f = (const float*)d_in[6];

    char* ws = (char*)d_ws;
    const size_t MB = 1ull << 20;
    __bf16*   qb    = (__bf16*)(ws + 0);            // 8 MB   (stage A)
    __bf16*   kvb   = (__bf16*)(ws + 8 * MB);       // 16 MB  (stage A)
    __bf16*   wqb   = (__bf16*)(ws + 24 * MB);      // 2 MB   (stage A)
    __bf16*   wkvb  = (__bf16*)(ws + 26 * MB);      // 4 MB   (stage A)
    _Float16* Opart = (_Float16*)(ws + 0);          // 16 MB  (stage B)
    float*    Lpart = (float*)(ws + 16 * MB);       // 0.5 MB (stage B)
    __bf16*   Yb    = (__bf16*)(ws + 17 * MB);      // 8 MB   (stage B)
    __bf16*   wob   = (__bf16*)(ws + 30 * MB);      // 2 MB
    __bf16*   Qp    = (__bf16*)(ws + 32 * MB);      // 8 MB
    __bf16*   Khd   = (__bf16*)(ws + 40 * MB);      // 16 MB
    __bf16*   Vhd   = (__bf16*)(ws + 56 * MB);      // 16 MB

    const float QSCALE = 0.125f * 1.4426950408889634f;

    f2b_multi<<<16384, 256, 0, stream>>>(q_f, kv_f, wq_f, wk_f, wv_f, wo_f,
                                         qb, kvb, wqb, wkvb, wob, QSCALE);

    proj_kernel<<<1280, 256, 0, stream>>>(qb, wqb, kvb, wkvb, Qp, Khd, Vhd, imp);

    attn_kernel<<<1024, 256, 0, stream>>>(Qp, Khd, Vhd, imp, Opart, Lpart);
    combine_kernel<<<2048, 256, 0, stream>>>(Opart, Lpart, Yb);

    gemm_out_kernel<<<dim3(8, 32), 256, 0, stream>>>(Yb, wob, (float*)d_out);
}

// Round 17
// 271.819 us; speedup vs baseline: 1.0437x; 1.0406x over previous
//
#include <hip/hip_runtime.h>
#include <hip/hip_bf16.h>

// ---------- types ----------
typedef __bf16    bf16x8_t __attribute__((ext_vector_type(8)));
typedef __bf16    bf16x4_t __attribute__((ext_vector_type(4)));
typedef float     f32x4_t  __attribute__((ext_vector_type(4)));
typedef float     f32x16_t __attribute__((ext_vector_type(16)));
typedef _Float16  f16x8_t  __attribute__((ext_vector_type(8)));
typedef unsigned int u32x2_t __attribute__((ext_vector_type(2)));
typedef unsigned int u32x4_t __attribute__((ext_vector_type(4)));

static __device__ __forceinline__ f32x4_t mfma16(bf16x8_t a, bf16x8_t b, f32x4_t c) {
    return __builtin_amdgcn_mfma_f32_16x16x32_bf16(a, b, c, 0, 0, 0);
}
static __device__ __forceinline__ f32x16_t mfma32(bf16x8_t a, bf16x8_t b, f32x16_t c) {
    return __builtin_amdgcn_mfma_f32_32x32x16_bf16(a, b, c, 0, 0, 0);
}
static __device__ __forceinline__ f32x16_t zero16() {
    f32x16_t z;
#pragma unroll
    for (int j = 0; j < 16; j++) z[j] = 0.f;
    return z;
}

// async global->LDS 16B (m97 pattern); lds pointer must be wave-uniform
static __device__ __forceinline__ void async16(const __bf16* g, __bf16* l) {
    __builtin_amdgcn_global_load_lds(
        (const __attribute__((address_space(1))) unsigned int*)g,
        (__attribute__((address_space(3))) unsigned int*)l, 16, 0, 0);
}

// ---------- fused fp32 -> bf16 convert ----------
__global__ __launch_bounds__(256) void f2b_multi(const float* __restrict__ q,
                                                 const float* __restrict__ kv,
                                                 const float* __restrict__ wq,
                                                 const float* __restrict__ wk,
                                                 const float* __restrict__ wv,
                                                 const float* __restrict__ wo,
                                                 __bf16* __restrict__ qb,
                                                 __bf16* __restrict__ kvb,
                                                 __bf16* __restrict__ wqb,
                                                 __bf16* __restrict__ wkvb,
                                                 __bf16* __restrict__ wob,
                                                 float qscale) {
    int i = blockIdx.x * 256 + threadIdx.x;
    const float* src; __bf16* dst; int base; float scale = 1.0f;
    if (i < 1048576)      { src = q;  dst = qb;   base = 0; }
    else if (i < 3145728) { src = kv; dst = kvb;  base = 1048576; }
    else if (i < 3407872) { src = wq; dst = wqb;  base = 3145728; scale = qscale; }
    else if (i < 3670016) { src = wk; dst = wkvb; base = 3407872; }
    else if (i < 3932160) { src = wv; dst = wkvb + 1048576; base = 3670016; }
    else                  { src = wo; dst = wob;  base = 3932160; }
    int j = i - base;
    float4 v = reinterpret_cast<const float4*>(src)[j];
    bf16x4_t o;
    o[0] = (__bf16)(v.x * scale); o[1] = (__bf16)(v.y * scale);
    o[2] = (__bf16)(v.z * scale); o[3] = (__bf16)(v.w * scale);
    reinterpret_cast<bf16x4_t*>(dst)[j] = o;
}

// ---------- merged projection GEMM: Q + K + V in one launch ----------
// grid 1280: gid<256 -> Qp = qb*wqb^T (row-major out); else KV tiles.
// Khd/Vhd: per 64-s tile, 16B-CHUNK-COLUMN-MAJOR (see attn).
// K-loop: single-barrier 2-phase double-buffer.
__global__ __launch_bounds__(256) void proj_kernel(const __bf16* __restrict__ qb,
                                                   const __bf16* __restrict__ wqb,
                                                   const __bf16* __restrict__ kvb,
                                                   const __bf16* __restrict__ wkvb,
                                                   __bf16* __restrict__ Qp,
                                                   __bf16* __restrict__ Khd,
                                                   __bf16* __restrict__ Vhd,
                                                   const float* __restrict__ imp) {
    __shared__ __bf16 As[2][4096];
    __shared__ __bf16 Bs[2][4096];

    const int gid = blockIdx.x;
    const __bf16 *A, *B;
    long m0, n0;
    int mode;   // 0=Q, 1=K-part, 2=V-part
    if (gid < 256) {
        m0 = (long)(gid >> 3) * 128; n0 = (long)(gid & 7) * 128;
        A = qb; B = wqb; mode = 0;
    } else {
        int g2 = gid - 256;
        m0 = (long)(g2 >> 4) * 128; n0 = (long)(g2 & 15) * 128;
        A = kvb; B = wkvb; mode = (n0 < 1024) ? 1 : 2;
    }

    const int t    = threadIdx.x;
    const int w    = t >> 6;
    const int lane = t & 63;
    const int quad = lane >> 4;
    const int mn   = lane & 15;
    const int wm   = (w & 1) * 64;
    const int wn   = (w >> 1) * 64;

    const int  srow = t >> 2;
    const int  scol = (t & 3) * 8;
    const __bf16* gA = A + (m0 + srow) * 1024 + scol;
    const __bf16* gB = B + (n0 + srow) * 1024 + scol;

    f32x4_t acc[4][4];
#pragma unroll
    for (int i = 0; i < 4; i++)
#pragma unroll
        for (int j = 0; j < 4; j++) acc[i][j] = (f32x4_t){0.f, 0.f, 0.f, 0.f};

    // prologue: stage k0=0 into buf 0
    async16(gA,             &As[0][t * 8]);
    async16(gA + 64 * 1024, &As[0][2048 + t * 8]);
    async16(gB,             &Bs[0][t * 8]);
    async16(gB + 64 * 1024, &Bs[0][2048 + t * 8]);
    __syncthreads();

    for (int k0 = 0; k0 < 1024; k0 += 32) {
        const int cur = (k0 >> 5) & 1;
        // issue next k-step into buf^1 (last iter: re-stage in-range, dead buf)
        const int kn = (k0 + 32 < 1024) ? k0 + 32 : k0;
        async16(gA + kn,             &As[cur ^ 1][t * 8]);
        async16(gA + 64 * 1024 + kn, &As[cur ^ 1][2048 + t * 8]);
        async16(gB + kn,             &Bs[cur ^ 1][t * 8]);
        async16(gB + 64 * 1024 + kn, &Bs[cur ^ 1][2048 + t * 8]);

        bf16x8_t af[4], bf[4];
#pragma unroll
        for (int i = 0; i < 4; i++)
            af[i] = *(const bf16x8_t*)&As[cur][(wm + i * 16 + mn) * 32 + quad * 8];
#pragma unroll
        for (int j = 0; j < 4; j++)
            bf[j] = *(const bf16x8_t*)&Bs[cur][(wn + j * 16 + mn) * 32 + quad * 8];
#pragma unroll
        for (int i = 0; i < 4; i++)
#pragma unroll
            for (int j = 0; j < 4; j++) acc[i][j] = mfma16(af[i], bf[j], acc[i][j]);

        // single drain point: next buf staged + all waves done reading cur
        __syncthreads();
    }

    // epilogue staging: per-wave 64x64 region carved from the dbuf space
    __bf16* stg = (w < 2) ? &As[w][0] : &Bs[w - 2][0];
    // swizzled LDS addr: (row, col) -> row*64 + ((col>>3)^(row&7))*8 + (col&7)

    if (mode != 2) {
#pragma unroll
        for (int i = 0; i < 4; i++)
#pragma unroll
            for (int j = 0; j < 4; j++)
#pragma unroll
                for (int r = 0; r < 4; r++) {
                    int sl = i * 16 + quad * 4 + r;
                    int d  = j * 16 + mn;
                    stg[sl * 64 + (((d >> 3) ^ (sl & 7)) * 8) + (d & 7)] =
                        (__bf16)acc[i][j][r];
                }
    } else {
        // V: store V^T[d][s_local] (plain s), scaled by clamped imp.
        const int b_ = (int)((m0 + wm) >> 12);
        float scl[4];
#pragma unroll
        for (int r = 0; r < 4; r++)
            scl[r] = fmaxf(imp[b_ * 16 + quad * 4 + r], 1e-6f);
#pragma unroll
        for (int i = 0; i < 4; i++)
#pragma unroll
            for (int j = 0; j < 4; j++) {
                bf16x4_t pk;
#pragma unroll
                for (int r = 0; r < 4; r++) pk[r] = (__bf16)(acc[i][j][r] * scl[r]);
                int d  = j * 16 + mn;
                int s0 = i * 16 + quad * 4;
                *(bf16x4_t*)&stg[d * 64 + (((s0 >> 3) ^ (d & 7)) * 8) + (s0 & 7)] = pk;
            }
    }

    if (mode == 0) {
        __bf16* Cg = Qp + (m0 + wm) * 1024 + (n0 + wn);
#pragma unroll
        for (int it = 0; it < 8; it++) {
            int rowL = it * 8 + (lane >> 3);
            int cb   = lane & 7;
            bf16x8_t vv = *(const bf16x8_t*)&stg[rowL * 64 + ((cb ^ (rowL & 7)) * 8)];
            *(bf16x8_t*)&Cg[(long)rowL * 1024 + cb * 8] = vv;
        }
    } else {
        const int b_    = (int)((m0 + wm) >> 12);
        const int sbase = (int)((m0 + wm) & 4095);
        __bf16* dst;
        if (mode == 1) {
            int h_ = (int)((n0 + wn) >> 6);
            dst = Khd + (long)(b_ * 16 + h_) * 262144 + (long)sbase * 64;
        } else {
            int h_ = (int)((n0 + wn) >> 6) - 16;
            dst = Vhd + (long)(b_ * 16 + h_) * 262144 + (long)(sbase >> 6) * 4096;
        }
        // chunk-column-major store: chunk(row=lane, c=it) -> dst[it*512 + lane*8]
#pragma unroll
        for (int it = 0; it < 8; it++) {
            bf16x8_t vv = *(const bf16x8_t*)&stg[lane * 64 + ((it ^ (lane & 7)) * 8)];
            *(bf16x8_t*)&dst[it * 512 + lane * 8] = vv;
        }
    }
}

// ---------- flash attention: swapped-QK 32x32 MFMA, in-register P, ----------
// single-barrier 2-phase pipeline. 1D grid 1024, XCD-swizzled:
// gid = (bh&7) | qt<<3 | sp<<7 | (bh>>3)<<8.
// K and V both double-buffered in LDS (chunk-col-major, identity staging).
// LDS = 2*8K (Ks) + 2*8K (Vs) = 32 KB -> 4 blocks/CU. Best measured: ~82.5 us.
__global__ __launch_bounds__(256, 4) void attn_kernel(const __bf16* __restrict__ Qp,
                                                      const __bf16* __restrict__ Kh,
                                                      const __bf16* __restrict__ Vh,
                                                      const float* __restrict__ imp,
                                                      _Float16* __restrict__ Op,
                                                      float* __restrict__ Lp) {
    const int gid = blockIdx.x;
    const int qt  = (gid >> 3) & 15;
    const int sp  = (gid >> 7) & 1;
    const int bh  = ((gid >> 8) << 3) | (gid & 7);
    const int b   = bh >> 4;
    const int h   = bh & 15;
    const int t    = threadIdx.x;
    const int w    = t >> 6;
    const int lane = t & 63;
    const int hi   = lane >> 5;
    const int q32  = lane & 31;

    __shared__ __bf16 Ks[2][4096];   // double-buffered K tile (chunk-col-major)
    __shared__ __bf16 Vs[2][4096];   // double-buffered V^T tile (chunk-col-major)

    const long qrow0 = (long)b * 2048 + qt * 128 + w * 32;
    const __bf16* Kb = Kh + (long)bh * 262144;
    const __bf16* Vb = Vh + (long)bh * 262144;

    // identity staging offsets (per wave, per issue): src offset == LDS offset
    const int off0 = w * 512 + lane * 8;
    const int off1 = 2048 + w * 512 + lane * 8;

    // Q fragments (B-operand): lane col q=q32, k = ks*16 + hi*8 + e
    bf16x8_t aq[4];
#pragma unroll
    for (int ks = 0; ks < 4; ks++)
        aq[ks] = *(const bf16x8_t*)&Qp[(qrow0 + q32) * 1024 + h * 64 + ks * 16 + hi * 8];

    float lp[2][4];
#pragma unroll
    for (int j = 0; j < 2; j++)
#pragma unroll
        for (int r = 0; r < 4; r++) lp[j][r] = 0.f;
    f32x16_t o0 = zero16(), o1 = zero16();
    // persistent zero C-operand for the first QK mfma of each s-half
    const f32x16_t z16 = zero16();

    const int st0 = sp * 32;

    // prologue: stage K[st0] -> Ks[0], V[st0] -> Vs[0]; drained by barrier
    async16(Kb + (long)st0 * 4096 + off0, &Ks[0][off0]);
    async16(Kb + (long)st0 * 4096 + off1, &Ks[0][off1]);
    async16(Vb + (long)st0 * 4096 + off0, &Vs[0][off0]);
    async16(Vb + (long)st0 * 4096 + off1, &Vs[0][off1]);
    __syncthreads();

    // per-lane fragment base within a chunk-col-major tile:
    // elem(row, c) = c*512 + row*8; lane reads c = 2ks+hi, row = q32 (+32)
    const int lanebase = hi * 512 + q32 * 8;

    for (int it = 0; it < 32; ++it) {
        const int cur = it & 1;
        // clamped next tile (it==31 re-stages tile 31 into the dead buffer)
        const long stn = (long)(st0 + ((it < 31) ? it + 1 : it)) * 4096;

        // issue-next FIRST: K[it+1] + V[it+1] -> buf^1; deadline is the
        // end-of-iteration barrier -> full QK+softmax+PV latency cover
        async16(Kb + stn + off0, &Ks[cur ^ 1][off0]);
        async16(Kb + stn + off1, &Ks[cur ^ 1][off1]);
        async16(Vb + stn + off0, &Vs[cur ^ 1][off0]);
        async16(Vb + stn + off1, &Vs[cur ^ 1][off1]);

        const __bf16* Kc = &Ks[cur][lanebase];
        bf16x8_t pa[4];

        // per s-half of 32: swapped QK^T -> softmax -> in-register PA build
#pragma unroll
        for (int st2 = 0; st2 < 2; st2++) {
            __builtin_amdgcn_s_setprio(1);
            bf16x8_t kf0 = *(const bf16x8_t*)&Kc[0 * 1024 + st2 * 256];
            f32x16_t sc = mfma32(kf0, aq[0], z16);
#pragma unroll
            for (int ks = 1; ks < 4; ks++) {
                bf16x8_t kf = *(const bf16x8_t*)&Kc[ks * 1024 + st2 * 256];
                sc = mfma32(kf, aq[ks], sc);
            }
            __builtin_amdgcn_s_setprio(0);

            // lane holds p[s_loc][q32], s_loc = j + 8*g + 4*hi (reg = 4g+j)
            unsigned int wv[8];
#pragma unroll
            for (int g = 0; g < 4; g++) {
                float p0 = __builtin_amdgcn_exp2f(sc[4 * g + 0]);
                float p1 = __builtin_amdgcn_exp2f(sc[4 * g + 1]);
                float p2 = __builtin_amdgcn_exp2f(sc[4 * g + 2]);
                float p3 = __builtin_amdgcn_exp2f(sc[4 * g + 3]);
                lp[g & 1][0] += p0; lp[g & 1][1] += p1;
                lp[g & 1][2] += p2; lp[g & 1][3] += p3;
                bf16x4_t pk;
                pk[0] = (__bf16)p0; pk[1] = (__bf16)p1;
                pk[2] = (__bf16)p2; pk[3] = (__bf16)p3;
                u32x2_t uu = __builtin_bit_cast(u32x2_t, pk);
                wv[2 * g]     = uu[0];
                wv[2 * g + 1] = uu[1];
            }
            // half-exchange: swap lanes>=32 of first arg with lanes<32 of second.
            u32x2_t s02 = __builtin_amdgcn_permlane32_swap(wv[0], wv[2], false, false);
            u32x2_t s13 = __builtin_amdgcn_permlane32_swap(wv[1], wv[3], false, false);
            u32x2_t s46 = __builtin_amdgcn_permlane32_swap(wv[4], wv[6], false, false);
            u32x2_t s57 = __builtin_amdgcn_permlane32_swap(wv[5], wv[7], false, false);
            u32x4_t pu0 = {s02[0], s13[0], s02[1], s13[1]};
            u32x4_t pu1 = {s46[0], s57[0], s46[1], s57[1]};
            pa[st2 * 2 + 0] = __builtin_bit_cast(bf16x8_t, pu0);
            pa[st2 * 2 + 1] = __builtin_bit_cast(bf16x8_t, pu1);
        }

        // PV: o[q][d] += sum_s PA[q][s] * V[s][d]; Vs rows = d, chunks = s/8.
        const __bf16* Vc = &Vs[cur][lanebase];
        __builtin_amdgcn_s_setprio(1);
#pragma unroll
        for (int ks = 0; ks < 4; ks++) {
            bf16x8_t v0 = *(const bf16x8_t*)&Vc[ks * 1024];
            bf16x8_t v1 = *(const bf16x8_t*)&Vc[ks * 1024 + 256];
            o0 = mfma32(pa[ks], v0, o0);
            o1 = mfma32(pa[ks], v1, o1);
        }
        __builtin_amdgcn_s_setprio(0);

        // single drain point: next K/V staged (covered by whole iteration),
        // and all waves done reading buf[cur] before it is overwritten.
        __syncthreads();
    }

    // epilogue: l[q] = sum exp * imp[sensor], sensor = 4*hi + 8*j + r
    float lsum = 0.f;
#pragma unroll
    for (int j = 0; j < 2; j++)
#pragma unroll
        for (int r = 0; r < 4; r++)
            lsum += lp[j][r] * fmaxf(imp[b * 16 + 4 * hi + 8 * j + r], 1e-6f);
    lsum += __shfl_xor(lsum, 32);
    if (lane < 32)
        Lp[((long)sp * 4096 + qrow0 + q32) * 16 + h] = lsum;

#pragma unroll
    for (int j = 0; j < 16; j++) {
        int q_loc = (j & 3) + 8 * (j >> 2) + 4 * hi;
        long row  = (long)sp * 4096 + qrow0 + q_loc;
        Op[row * 1024 + h * 64 + 0 * 32 + q32] = (_Float16)o0[j];
        Op[row * 1024 + h * 64 + 1 * 32 + q32] = (_Float16)o1[j];
    }
}

// ---------- combine: Y = (o0+o1)/(l0+l1) ----------
__global__ __launch_bounds__(256) void combine_kernel(const _Float16* __restrict__ Op,
                                                      const float* __restrict__ Lp,
                                                      __bf16* __restrict__ Y) {
    int tid = blockIdx.x * 256 + threadIdx.x;
    int row = tid >> 7;
    int cg  = tid & 127;
    int h   = cg >> 3;
    f16x8_t o0 = *(const f16x8_t*)&Op[(long)row * 1024 + cg * 8];
    f16x8_t o1 = *(const f16x8_t*)&Op[(long)(4096 + row) * 1024 + cg * 8];
    float inv = 1.0f / (Lp[row * 16 + h] + Lp[(4096 + row) * 16 + h]);
    bf16x8_t y;
#pragma unroll
    for (int j = 0; j < 8; j++) y[j] = (__bf16)(((float)o0[j] + (float)o1[j]) * inv);
    *(bf16x8_t*)&Y[(long)row * 1024 + cg * 8] = y;
}

// ---------- output GEMM, split-M full-K: out = Yb * wob^T, fp32 direct ----------
// grid dim3(8, 64): n-tile = blockIdx.x (128 cols), m-tile = blockIdx.y (64
// rows). 512 blocks = 2/CU (restores R15-era concurrency WITHOUT split-K
// partials: no Gp, no combine2). Tile 64x128, 4 waves in 2x2 (wave = 32x64,
// acc 2x4). LDS = dbuf (4K A + 8K B) = 24 KB.
__global__ __launch_bounds__(256) void gemm_out_kernel(const __bf16* __restrict__ A,
                                                       const __bf16* __restrict__ B,
                                                       float* __restrict__ C) {
    __shared__ __bf16 As[2][2048];
    __shared__ __bf16 Bs[2][4096];

    const long n0 = (long)blockIdx.x * 128;
    const long m0 = (long)blockIdx.y * 64;

    const int t    = threadIdx.x;
    const int w    = t >> 6;
    const int lane = t & 63;
    const int quad = lane >> 4;
    const int mn   = lane & 15;
    const int wm   = (w & 1) * 32;   // wave m-offset (2 waves over 64 rows)
    const int wn   = (w >> 1) * 64;  // wave n-offset (2 waves over 128 cols)

    // A staging: 64 rows x 32 k; thread t -> row t>>2, k-chunk (t&3)*8 (1 issue)
    const int  srowA = t >> 2;
    const int  scolA = (t & 3) * 8;
    // B staging: 128 rows x 32 k; two issues of 64 rows each
    const __bf16* gA = A + (m0 + srowA) * 1024 + scolA;
    const __bf16* gB = B + (n0 + srowA) * 1024 + scolA;

    f32x4_t acc[2][4];
#pragma unroll
    for (int i = 0; i < 2; i++)
#pragma unroll
        for (int j = 0; j < 4; j++) acc[i][j] = (f32x4_t){0.f, 0.f, 0.f, 0.f};

    // prologue: stage k0=0 into buf 0
    async16(gA,             &As[0][t * 8]);
    async16(gB,             &Bs[0][t * 8]);
    async16(gB + 64 * 1024, &Bs[0][2048 + t * 8]);
    __syncthreads();

    for (int k0 = 0; k0 < 1024; k0 += 32) {
        const int cur = (k0 >> 5) & 1;
        const int kn = (k0 + 32 < 1024) ? k0 + 32 : k0;
        async16(gA + kn,             &As[cur ^ 1][t * 8]);
        async16(gB + kn,             &Bs[cur ^ 1][t * 8]);
        async16(gB + 64 * 1024 + kn, &Bs[cur ^ 1][2048 + t * 8]);

        bf16x8_t af[2], bf[4];
#pragma unroll
        for (int i = 0; i < 2; i++)
            af[i] = *(const bf16x8_t*)&As[cur][(wm + i * 16 + mn) * 32 + quad * 8];
#pragma unroll
        for (int j = 0; j < 4; j++)
            bf[j] = *(const bf16x8_t*)&Bs[cur][(wn + j * 16 + mn) * 32 + quad * 8];
#pragma unroll
        for (int i = 0; i < 2; i++)
#pragma unroll
            for (int j = 0; j < 4; j++) acc[i][j] = mfma16(af[i], bf[j], acc[i][j]);

        __syncthreads();
    }

#pragma unroll
    for (int i = 0; i < 2; i++)
#pragma unroll
        for (int j = 0; j < 4; j++)
#pragma unroll
            for (int r = 0; r < 4; r++) {
                long row = m0 + wm + i * 16 + quad * 4 + r;
                long col = n0 + wn + j * 16 + mn;
                C[row * 1024 + col] = acc[i][j][r];
            }
}

// ---------- launch ----------
extern "C" void kernel_launch(void* const* d_in, const int* in_sizes, int n_in,
                              void* d_out, int out_size, void* d_ws, size_t ws_size,
                              hipStream_t stream) {
    const float* q_f  = (const float*)d_in[0];
    const float* kv_f = (const float*)d_in[1];
    const float* imp  = (const float*)d_in[2];
    const float* wq_f = (const float*)d_in[3];
    const float* wk_f = (const float*)d_in[4];
    const float* wv_f = (const float*)d_in[5];
    const float* wo_f = (const float*)d_in[6];

    char* ws = (char*)d_ws;
    const size_t MB = 1ull << 20;
    __bf16*   qb    = (__bf16*)(ws + 0);            // 8 MB   (stage A)
    __bf16*   kvb   = (__bf16*)(ws + 8 * MB);       // 16 MB  (stage A)
    __bf16*   wqb   = (__bf16*)(ws + 24 * MB);      // 2 MB   (stage A)
    __bf16*   wkvb  = (__bf16*)(ws + 26 * MB);      // 4 MB   (stage A)
    _Float16* Opart = (_Float16*)(ws + 0);          // 16 MB  (stage B)
    float*    Lpart = (float*)(ws + 16 * MB);       // 0.5 MB (stage B)
    __bf16*   Yb    = (__bf16*)(ws + 17 * MB);      // 8 MB   (stage B)
    __bf16*   wob   = (__bf16*)(ws + 30 * MB);      // 2 MB
    __bf16*   Qp    = (__bf16*)(ws + 32 * MB);      // 8 MB
    __bf16*   Khd   = (__bf16*)(ws + 40 * MB);      // 16 MB
    __bf16*   Vhd   = (__bf16*)(ws + 56 * MB);      // 16 MB

    const float QSCALE = 0.125f * 1.4426950408889634f;

    f2b_multi<<<16384, 256, 0, stream>>>(q_f, kv_f, wq_f, wk_f, wv_f, wo_f,
                                         qb, kvb, wqb, wkvb, wob, QSCALE);

    proj_kernel<<<1280, 256, 0, stream>>>(qb, wqb, kvb, wkvb, Qp, Khd, Vhd, imp);

    attn_kernel<<<1024, 256, 0, stream>>>(Qp, Khd, Vhd, imp, Opart, Lpart);
    combine_kernel<<<2048, 256, 0, stream>>>(Opart, Lpart, Yb);

    gemm_out_kernel<<<dim3(8, 64), 256, 0, stream>>>(Yb, wob, (float*)d_out);
}